// Round 1
// baseline (681.685 us; speedup 1.0000x reference)
//
#include <hip/hip_runtime.h>

#define NN 8192
#define DD 256
#define SCALE (1.0f / 0.07f)

typedef __attribute__((ext_vector_type(8))) short short8;
typedef __attribute__((ext_vector_type(4))) float f32x4;

// ---- helpers -------------------------------------------------------------

__device__ inline unsigned short f2bf(float x) {
    unsigned u = __float_as_uint(x);
    u += 0x7fffu + ((u >> 16) & 1u);   // round-to-nearest-even
    return (unsigned short)(u >> 16);
}

// Merge a partial (m_in, s_in) logsumexp state into *addr, packed as
// [s (hi 32)] [m (lo 32)], via 64-bit CAS loop. Init state is (-inf, 0).
__device__ inline void lse_merge(unsigned long long* addr, float m_in, float s_in) {
    unsigned long long old = *addr;
    while (true) {
        float m_old = __uint_as_float((unsigned)(old & 0xffffffffull));
        float s_old = __uint_as_float((unsigned)(old >> 32));
        float m_new = fmaxf(m_old, m_in);
        // m_old==-inf, s_old==0: 0*expf(-inf)=0*0=0 -> ok, no NaN
        float s_new = s_old * __expf(m_old - m_new) + s_in * __expf(m_in - m_new);
        unsigned long long nv =
            ((unsigned long long)__float_as_uint(s_new) << 32) |
            (unsigned long long)__float_as_uint(m_new);
        unsigned long long prev = atomicCAS(addr, old, nv);
        if (prev == old) break;
        old = prev;
    }
}

// ---- kernels -------------------------------------------------------------

__global__ __launch_bounds__(256) void init_kernel(unsigned long long* row_acc,
                                                   unsigned long long* col_acc,
                                                   float* out) {
    int i = blockIdx.x * 256 + threadIdx.x;
    unsigned long long v = (unsigned long long)__float_as_uint(-INFINITY); // s=0 in hi bits
    if (i < NN) { row_acc[i] = v; col_acc[i] = v; }
    if (i == 0) out[0] = 0.0f;
}

__global__ __launch_bounds__(256) void convert_kernel(const float* __restrict__ I,
                                                      const float* __restrict__ C,
                                                      unsigned short* __restrict__ Ib,
                                                      unsigned short* __restrict__ Cb) {
    int i = blockIdx.x * 256 + threadIdx.x;     // 524288 float4 chunks per array
    float4 a = ((const float4*)I)[i];
    float4 b = ((const float4*)C)[i];
    ushort4 oa = make_ushort4(f2bf(a.x), f2bf(a.y), f2bf(a.z), f2bf(a.w));
    ushort4 ob = make_ushort4(f2bf(b.x), f2bf(b.y), f2bf(b.z), f2bf(b.w));
    ((ushort4*)Ib)[i] = oa;
    ((ushort4*)Cb)[i] = ob;
}

// Exact fp32 diagonal: diag[i] = dot(I[i], C[i]) * SCALE. One wave per row.
__global__ __launch_bounds__(256) void diag_kernel(const float* __restrict__ I,
                                                   const float* __restrict__ C,
                                                   float* __restrict__ diag) {
    int wave = threadIdx.x >> 6, lane = threadIdx.x & 63;
    int row = blockIdx.x * 4 + wave;
    float4 a = ((const float4*)(I + (size_t)row * DD))[lane];
    float4 b = ((const float4*)(C + (size_t)row * DD))[lane];
    float s = a.x * b.x + a.y * b.y + a.z * b.z + a.w * b.w;
    #pragma unroll
    for (int off = 32; off >= 1; off >>= 1) s += __shfl_xor(s, off);
    if (lane == 0) diag[row] = s * SCALE;
}

// 128x128 logits tile per block; bf16 MFMA; online row/col LSE epilogue.
__global__ __launch_bounds__(256) void gemm_lse_kernel(
        const unsigned short* __restrict__ Ib,
        const unsigned short* __restrict__ Cb,
        unsigned long long* __restrict__ row_acc,
        unsigned long long* __restrict__ col_acc) {
    // +8 pad: 144B row stride -> conflict-free ds_read_b128 fragment reads
    __shared__ __align__(16) unsigned short As[128][72];
    __shared__ __align__(16) unsigned short Bs[128][72];

    const int i0 = blockIdx.y * 128;
    const int j0 = blockIdx.x * 128;
    const int t = threadIdx.x;
    const int wave = t >> 6, lane = t & 63;
    const int wr = wave >> 1, wc = wave & 1;   // 2x2 wave grid, each wave 64x64
    const int q = lane >> 4, cl = lane & 15;   // quad, col-lane

    f32x4 acc[4][4];
    #pragma unroll
    for (int mi = 0; mi < 4; ++mi)
        #pragma unroll
        for (int ni = 0; ni < 4; ++ni)
            acc[mi][ni] = (f32x4){0.f, 0.f, 0.f, 0.f};

    const int lrow = t >> 3;   // staging row (0..31, + it*32)
    const int lkc  = t & 7;    // staging k-chunk (8 bf16 = 16B each)

    for (int kk = 0; kk < DD; kk += 64) {
        #pragma unroll
        for (int it = 0; it < 4; ++it) {
            int row = lrow + it * 32;
            float4 va = *(const float4*)(Ib + (size_t)(i0 + row) * DD + kk + lkc * 8);
            *(float4*)&As[row][lkc * 8] = va;
            float4 vb = *(const float4*)(Cb + (size_t)(j0 + row) * DD + kk + lkc * 8);
            *(float4*)&Bs[row][lkc * 8] = vb;
        }
        __syncthreads();
        #pragma unroll
        for (int ks = 0; ks < 2; ++ks) {
            short8 af[4], bfr[4];
            #pragma unroll
            for (int mi = 0; mi < 4; ++mi)
                af[mi] = *(const short8*)&As[wr * 64 + mi * 16 + cl][ks * 32 + q * 8];
            #pragma unroll
            for (int ni = 0; ni < 4; ++ni)
                bfr[ni] = *(const short8*)&Bs[wc * 64 + ni * 16 + cl][ks * 32 + q * 8];
            #pragma unroll
            for (int mi = 0; mi < 4; ++mi)
                #pragma unroll
                for (int ni = 0; ni < 4; ++ni)
                    acc[mi][ni] = __builtin_amdgcn_mfma_f32_16x16x32_bf16(
                        af[mi], bfr[ni], acc[mi][ni], 0, 0, 0);
        }
        __syncthreads();
    }

    // scale logits
    #pragma unroll
    for (int mi = 0; mi < 4; ++mi)
        #pragma unroll
        for (int ni = 0; ni < 4; ++ni)
            #pragma unroll
            for (int r = 0; r < 4; ++r)
                acc[mi][ni][r] *= SCALE;

    // ---- row statistics: each tile row lives in 16 lanes of one quad ----
    // C/D mapping: col = lane&15, row = quad*4 + reg
    #pragma unroll
    for (int mi = 0; mi < 4; ++mi) {
        #pragma unroll
        for (int r = 0; r < 4; ++r) {
            float m = fmaxf(fmaxf(acc[mi][0][r], acc[mi][1][r]),
                            fmaxf(acc[mi][2][r], acc[mi][3][r]));
            #pragma unroll
            for (int off = 8; off >= 1; off >>= 1) m = fmaxf(m, __shfl_xor(m, off));
            float s = __expf(acc[mi][0][r] - m) + __expf(acc[mi][1][r] - m) +
                      __expf(acc[mi][2][r] - m) + __expf(acc[mi][3][r] - m);
            #pragma unroll
            for (int off = 8; off >= 1; off >>= 1) s += __shfl_xor(s, off);
            if (cl == 0)
                lse_merge(&row_acc[i0 + wr * 64 + mi * 16 + q * 4 + r], m, s);
        }
    }

    // ---- column statistics: a column lives in lanes {q*16+cl : q=0..3} ----
    #pragma unroll
    for (int ni = 0; ni < 4; ++ni) {
        float m = -INFINITY;
        #pragma unroll
        for (int mi = 0; mi < 4; ++mi)
            #pragma unroll
            for (int r = 0; r < 4; ++r)
                m = fmaxf(m, acc[mi][ni][r]);
        m = fmaxf(m, __shfl_xor(m, 16));
        m = fmaxf(m, __shfl_xor(m, 32));
        float s = 0.f;
        #pragma unroll
        for (int mi = 0; mi < 4; ++mi)
            #pragma unroll
            for (int r = 0; r < 4; ++r)
                s += __expf(acc[mi][ni][r] - m);
        s += __shfl_xor(s, 16);
        s += __shfl_xor(s, 32);
        if (q == 0)
            lse_merge(&col_acc[j0 + wc * 64 + ni * 16 + cl], m, s);
    }
}

__global__ __launch_bounds__(256) void finish_kernel(
        const unsigned long long* __restrict__ row_acc,
        const unsigned long long* __restrict__ col_acc,
        const float* __restrict__ diag, float* out) {
    int i = blockIdx.x * 256 + threadIdx.x;
    unsigned long long r = row_acc[i], c = col_acc[i];
    float rm = __uint_as_float((unsigned)(r & 0xffffffffull));
    float rs = __uint_as_float((unsigned)(r >> 32));
    float cm = __uint_as_float((unsigned)(c & 0xffffffffull));
    float cs = __uint_as_float((unsigned)(c >> 32));
    float d = diag[i];
    float v = ((rm + logf(rs) - d) + (cm + logf(cs) - d)) * (0.5f / (float)NN);
    #pragma unroll
    for (int off = 32; off >= 1; off >>= 1) v += __shfl_xor(v, off);
    __shared__ float red[4];
    int wave = threadIdx.x >> 6, lane = threadIdx.x & 63;
    if (lane == 0) red[wave] = v;
    __syncthreads();
    if (threadIdx.x == 0) atomicAdd(out, red[0] + red[1] + red[2] + red[3]);
}

// ---- launch --------------------------------------------------------------

extern "C" void kernel_launch(void* const* d_in, const int* in_sizes, int n_in,
                              void* d_out, int out_size, void* d_ws, size_t ws_size,
                              hipStream_t stream) {
    const float* I = (const float*)d_in[0];
    const float* C = (const float*)d_in[1];
    float* out = (float*)d_out;
    char* ws = (char*)d_ws;

    // workspace layout (needs ~8.2 MB)
    unsigned short* Ib = (unsigned short*)ws;                         // 4 MB
    unsigned short* Cb = (unsigned short*)(ws + 4u * 1024 * 1024);    // 4 MB
    unsigned long long* row_acc = (unsigned long long*)(ws + 8u * 1024 * 1024);        // 64 KB
    unsigned long long* col_acc = (unsigned long long*)(ws + 8u * 1024 * 1024 + 65536); // 64 KB
    float* diag = (float*)(ws + 8u * 1024 * 1024 + 131072);           // 32 KB

    init_kernel<<<32, 256, 0, stream>>>(row_acc, col_acc, out);
    convert_kernel<<<2048, 256, 0, stream>>>(I, C, Ib, Cb);
    diag_kernel<<<2048, 256, 0, stream>>>(I, C, diag);
    dim3 grid(64, 64);
    gemm_lse_kernel<<<grid, 256, 0, stream>>>(Ib, Cb, row_acc, col_acc);
    finish_kernel<<<32, 256, 0, stream>>>(row_acc, col_acc, diag, out);
}

// Round 3
// 171.666 us; speedup vs baseline: 3.9710x; 3.9710x over previous
//
#include <hip/hip_runtime.h>

#define NN 8192
#define DD 256
#define SCALE (1.0f / 0.07f)

typedef __attribute__((ext_vector_type(8))) short short8;
typedef __attribute__((ext_vector_type(4))) float f32x4;

// ---- helpers -------------------------------------------------------------

__device__ inline unsigned short f2bf(float x) {
    unsigned u = __float_as_uint(x);
    u += 0x7fffu + ((u >> 16) & 1u);   // round-to-nearest-even
    return (unsigned short)(u >> 16);
}

__device__ inline unsigned long long pack_ms(float m, float s) {
    return ((unsigned long long)__float_as_uint(s) << 32) |
           (unsigned long long)__float_as_uint(m);
}

__device__ inline unsigned long long merge_ms(unsigned long long a,
                                              unsigned long long b) {
    float ma = __uint_as_float((unsigned)(a & 0xffffffffull));
    float sa = __uint_as_float((unsigned)(a >> 32));
    float mb = __uint_as_float((unsigned)(b & 0xffffffffull));
    float sb = __uint_as_float((unsigned)(b >> 32));
    float m = fmaxf(ma, mb);
    float s = sa * __expf(ma - m) + sb * __expf(mb - m);
    return pack_ms(m, s);
}

// ---- kernels -------------------------------------------------------------

__global__ __launch_bounds__(64) void zero_out_kernel(float* out) {
    if (threadIdx.x == 0) out[0] = 0.0f;
}

__global__ __launch_bounds__(256) void convert_kernel(const float* __restrict__ I,
                                                      const float* __restrict__ C,
                                                      unsigned short* __restrict__ Ib,
                                                      unsigned short* __restrict__ Cb) {
    int i = blockIdx.x * 256 + threadIdx.x;     // 524288 float4 chunks per array
    float4 a = ((const float4*)I)[i];
    float4 b = ((const float4*)C)[i];
    ushort4 oa = make_ushort4(f2bf(a.x), f2bf(a.y), f2bf(a.z), f2bf(a.w));
    ushort4 ob = make_ushort4(f2bf(b.x), f2bf(b.y), f2bf(b.z), f2bf(b.w));
    ((ushort4*)Ib)[i] = oa;
    ((ushort4*)Cb)[i] = ob;
}

// Exact fp32 diagonal: diag[i] = dot(I[i], C[i]) * SCALE. One wave per row.
__global__ __launch_bounds__(256) void diag_kernel(const float* __restrict__ I,
                                                   const float* __restrict__ C,
                                                   float* __restrict__ diag) {
    int wave = threadIdx.x >> 6, lane = threadIdx.x & 63;
    int row = blockIdx.x * 4 + wave;
    float4 a = ((const float4*)(I + (size_t)row * DD))[lane];
    float4 b = ((const float4*)(C + (size_t)row * DD))[lane];
    float s = a.x * b.x + a.y * b.y + a.z * b.z + a.w * b.w;
    #pragma unroll
    for (int off = 32; off >= 1; off >>= 1) s += __shfl_xor(s, off);
    if (lane == 0) diag[row] = s * SCALE;
}

// 128x128 logits tile per block; bf16 MFMA via global_load_lds staging with
// XOR chunk swizzle; per-tile row/col (m, sum-exp) -> LDS merge -> partials.
__global__ __launch_bounds__(256) void gemm_lse_kernel(
        const unsigned short* __restrict__ Ib,
        const unsigned short* __restrict__ Cb,
        unsigned long long* __restrict__ row_part,   // [64 (bx)][NN]
        unsigned long long* __restrict__ col_part) { // [64 (by)][NN]
    __shared__ __align__(16) unsigned short As[128][64];
    __shared__ __align__(16) unsigned short Bs[128][64];
    __shared__ unsigned long long rowms[2][128];     // [wc][tile row]
    __shared__ unsigned long long colms[2][128];     // [wr][tile col]

    const int i0 = blockIdx.y * 128;
    const int j0 = blockIdx.x * 128;
    const int t = threadIdx.x;
    const int wave = t >> 6, lane = t & 63;
    const int wr = wave >> 1, wc = wave & 1;   // 2x2 wave grid, each wave 64x64
    const int q = lane >> 4, cl = lane & 15;   // quad, col-lane

    f32x4 acc[4][4];
    #pragma unroll
    for (int mi = 0; mi < 4; ++mi)
        #pragma unroll
        for (int ni = 0; ni < 4; ++ni)
            acc[mi][ni] = (f32x4){0.f, 0.f, 0.f, 0.f};

    // Staging: waves 0,1 -> As halves; waves 2,3 -> Bs halves.
    // Each issue: 64 lanes x 16B = 1 KB = 8 LDS rows (lane>>3 = row-in-issue,
    // lane&7 = physical 16B chunk). XOR swizzle: physical chunk p of row r
    // holds logical chunk p ^ (r & 7), so this lane fetches logical chunk
    // (lane&7) ^ (lane>>3) from global.
    const int half = wave & 1;
    const unsigned short* sbase = (wave < 2)
        ? (Ib + (size_t)(i0 + half * 64) * DD)
        : (Cb + (size_t)(j0 + half * 64) * DD);
    const int srow = lane >> 3;                 // row within each 8-row issue
    const int schunk = (lane & 7) ^ srow;       // logical chunk index (0..7)

    for (int kk = 0; kk < DD; kk += 64) {
        #pragma unroll
        for (int it = 0; it < 8; ++it) {
            const unsigned short* g =
                sbase + (size_t)(it * 8 + srow) * DD + kk + schunk * 8;
            unsigned short* ldsbase = (wave < 2) ? &As[half * 64 + it * 8][0]
                                                 : &Bs[half * 64 + it * 8][0];
            __builtin_amdgcn_global_load_lds(
                (const __attribute__((address_space(1))) void*)g,
                (__attribute__((address_space(3))) void*)ldsbase,
                16, 0, 0);
        }
        __syncthreads();
        #pragma unroll
        for (int ks = 0; ks < 2; ++ks) {
            short8 af[4], bfr[4];
            const int pa = ((ks * 4 + q) ^ (cl & 7)) * 8;  // swizzled elem offset
            #pragma unroll
            for (int mi = 0; mi < 4; ++mi)
                af[mi] = *(const short8*)&As[wr * 64 + mi * 16 + cl][pa];
            #pragma unroll
            for (int ni = 0; ni < 4; ++ni)
                bfr[ni] = *(const short8*)&Bs[wc * 64 + ni * 16 + cl][pa];
            #pragma unroll
            for (int mi = 0; mi < 4; ++mi)
                #pragma unroll
                for (int ni = 0; ni < 4; ++ni)
                    acc[mi][ni] = __builtin_amdgcn_mfma_f32_16x16x32_bf16(
                        af[mi], bfr[ni], acc[mi][ni], 0, 0, 0);
        }
        __syncthreads();
    }

    // scale logits
    #pragma unroll
    for (int mi = 0; mi < 4; ++mi)
        #pragma unroll
        for (int ni = 0; ni < 4; ++ni)
            #pragma unroll
            for (int r = 0; r < 4; ++r)
                acc[mi][ni][r] *= SCALE;

    // ---- per-wave row stats (64-col slice wc): col = lane&15, row = q*4+r --
    #pragma unroll
    for (int mi = 0; mi < 4; ++mi) {
        #pragma unroll
        for (int r = 0; r < 4; ++r) {
            float m = fmaxf(fmaxf(acc[mi][0][r], acc[mi][1][r]),
                            fmaxf(acc[mi][2][r], acc[mi][3][r]));
            #pragma unroll
            for (int off = 8; off >= 1; off >>= 1) m = fmaxf(m, __shfl_xor(m, off));
            float s = __expf(acc[mi][0][r] - m) + __expf(acc[mi][1][r] - m) +
                      __expf(acc[mi][2][r] - m) + __expf(acc[mi][3][r] - m);
            #pragma unroll
            for (int off = 8; off >= 1; off >>= 1) s += __shfl_xor(s, off);
            if (cl == 0)
                rowms[wc][wr * 64 + mi * 16 + q * 4 + r] = pack_ms(m, s);
        }
    }

    // ---- per-wave col stats (64-row slice wr): col j lives in lanes q*16+j --
    #pragma unroll
    for (int ni = 0; ni < 4; ++ni) {
        float m = -INFINITY;
        #pragma unroll
        for (int mi = 0; mi < 4; ++mi)
            #pragma unroll
            for (int r = 0; r < 4; ++r)
                m = fmaxf(m, acc[mi][ni][r]);
        m = fmaxf(m, __shfl_xor(m, 16));
        m = fmaxf(m, __shfl_xor(m, 32));
        float s = 0.f;
        #pragma unroll
        for (int mi = 0; mi < 4; ++mi)
            #pragma unroll
            for (int r = 0; r < 4; ++r)
                s += __expf(acc[mi][ni][r] - m);
        s += __shfl_xor(s, 16);
        s += __shfl_xor(s, 32);
        if (q == 0)
            colms[wr][wc * 64 + ni * 16 + cl] = pack_ms(m, s);
    }

    __syncthreads();

    // ---- merge the two half-contributions, one store per row/col ----------
    if (t < 128) {
        row_part[(size_t)blockIdx.x * NN + i0 + t] =
            merge_ms(rowms[0][t], rowms[1][t]);
    } else {
        int c = t - 128;
        col_part[(size_t)blockIdx.y * NN + j0 + c] =
            merge_ms(colms[0][c], colms[1][c]);
    }
}

// Merge 64 partials per row and per col, combine with diag, reduce to loss.
// idx < NN -> row stats; idx >= NN -> col stats. Coalesced: thread = row.
__global__ __launch_bounds__(256) void reduce_kernel(
        const unsigned long long* __restrict__ row_part,
        const unsigned long long* __restrict__ col_part,
        const float* __restrict__ diag, float* out) {
    int idx = blockIdx.x * 256 + threadIdx.x;      // 0 .. 2*NN-1
    int r = (idx >= NN) ? idx - NN : idx;
    const unsigned long long* part = (idx >= NN) ? col_part : row_part;
    float m = -INFINITY, s = 0.f;
    #pragma unroll 4
    for (int p = 0; p < 64; ++p) {
        unsigned long long v = part[(size_t)p * NN + r];
        float pm = __uint_as_float((unsigned)(v & 0xffffffffull));
        float ps = __uint_as_float((unsigned)(v >> 32));
        float nm = fmaxf(m, pm);
        s = s * __expf(m - nm) + ps * __expf(pm - nm);
        m = nm;
    }
    float v = (m + logf(s) - diag[r]) * (0.5f / (float)NN);
    #pragma unroll
    for (int off = 32; off >= 1; off >>= 1) v += __shfl_xor(v, off);
    __shared__ float red[4];
    int wv = threadIdx.x >> 6, lane = threadIdx.x & 63;
    if (lane == 0) red[wv] = v;
    __syncthreads();
    if (threadIdx.x == 0) atomicAdd(out, red[0] + red[1] + red[2] + red[3]);
}

// ---- launch --------------------------------------------------------------

extern "C" void kernel_launch(void* const* d_in, const int* in_sizes, int n_in,
                              void* d_out, int out_size, void* d_ws, size_t ws_size,
                              hipStream_t stream) {
    const float* I = (const float*)d_in[0];
    const float* C = (const float*)d_in[1];
    float* out = (float*)d_out;
    char* ws = (char*)d_ws;

    // workspace layout (~16.1 MB)
    unsigned short* Ib = (unsigned short*)ws;                              // 4 MB
    unsigned short* Cb = (unsigned short*)(ws + (size_t)4 * 1024 * 1024);  // 4 MB
    unsigned long long* row_part =
        (unsigned long long*)(ws + (size_t)8 * 1024 * 1024);               // 4 MB
    unsigned long long* col_part =
        (unsigned long long*)(ws + (size_t)12 * 1024 * 1024);              // 4 MB
    float* diag = (float*)(ws + (size_t)16 * 1024 * 1024);                 // 32 KB

    zero_out_kernel<<<1, 64, 0, stream>>>(out);
    convert_kernel<<<2048, 256, 0, stream>>>(I, C, Ib, Cb);
    diag_kernel<<<2048, 256, 0, stream>>>(I, C, diag);
    dim3 grid(64, 64);
    gemm_lse_kernel<<<grid, 256, 0, stream>>>(Ib, Cb, row_part, col_part);
    reduce_kernel<<<64, 256, 0, stream>>>(row_part, col_part, diag, out);
}

// Round 4
// 142.721 us; speedup vs baseline: 4.7764x; 1.2028x over previous
//
#include <hip/hip_runtime.h>

#define NN 8192
#define DD 256
#define SCALE (1.0f / 0.07f)
// sqrt(1/0.07): folded into both bf16 operands so MFMA output = logits directly
#define SQRT_SCALE 3.7796447300922722f

typedef __attribute__((ext_vector_type(8))) short short8;
typedef __attribute__((ext_vector_type(4))) float f32x4;

// ---- helpers -------------------------------------------------------------

__device__ inline unsigned short f2bf(float x) {
    unsigned u = __float_as_uint(x);
    u += 0x7fffu + ((u >> 16) & 1u);   // round-to-nearest-even
    return (unsigned short)(u >> 16);
}

__device__ inline unsigned long long pack_ms(float m, float s) {
    return ((unsigned long long)__float_as_uint(s) << 32) |
           (unsigned long long)__float_as_uint(m);
}

__device__ inline unsigned long long merge_ms(unsigned long long a,
                                              unsigned long long b) {
    float ma = __uint_as_float((unsigned)(a & 0xffffffffull));
    float sa = __uint_as_float((unsigned)(a >> 32));
    float mb = __uint_as_float((unsigned)(b & 0xffffffffull));
    float sb = __uint_as_float((unsigned)(b >> 32));
    float m = fmaxf(ma, mb);
    float s = sa * __expf(ma - m) + sb * __expf(mb - m);
    return pack_ms(m, s);
}

// ---- kernels -------------------------------------------------------------

// Fused: bf16 convert (with sqrt(SCALE) pre-scaling) + exact fp32 diagonal
// + out zeroing. One wave = 64 float4 chunks = exactly one 256-elem row.
__global__ __launch_bounds__(256) void convert_diag_kernel(
        const float* __restrict__ I, const float* __restrict__ C,
        unsigned short* __restrict__ Ib, unsigned short* __restrict__ Cb,
        float* __restrict__ diag, float* out) {
    if (blockIdx.x == 0 && threadIdx.x == 0) out[0] = 0.0f;
    int i = blockIdx.x * 256 + threadIdx.x;     // float4 chunk id
    float4 a = ((const float4*)I)[i];
    float4 b = ((const float4*)C)[i];
    ushort4 oa = make_ushort4(f2bf(a.x * SQRT_SCALE), f2bf(a.y * SQRT_SCALE),
                              f2bf(a.z * SQRT_SCALE), f2bf(a.w * SQRT_SCALE));
    ushort4 ob = make_ushort4(f2bf(b.x * SQRT_SCALE), f2bf(b.y * SQRT_SCALE),
                              f2bf(b.z * SQRT_SCALE), f2bf(b.w * SQRT_SCALE));
    ((ushort4*)Ib)[i] = oa;
    ((ushort4*)Cb)[i] = ob;
    float s = a.x * b.x + a.y * b.y + a.z * b.z + a.w * b.w;
    #pragma unroll
    for (int off = 32; off >= 1; off >>= 1) s += __shfl_xor(s, off);
    if ((threadIdx.x & 63) == 0) diag[i >> 6] = s * SCALE;
}

// 128x128 logits tile per block. Dual-product trick: acc = A*B^T and
// acc2 = B*A^T from the SAME LDS fragments, so both row and col LSE stats
// use the cheap in-register direction (16 in-reg + 2 shuffles) instead of
// 4-level 16-lane shuffle trees.
__global__ __launch_bounds__(256, 2) void gemm_lse_kernel(
        const unsigned short* __restrict__ Ib,
        const unsigned short* __restrict__ Cb,
        unsigned long long* __restrict__ row_part,   // [64 (bx)][NN]
        unsigned long long* __restrict__ col_part) { // [64 (by)][NN]
    __shared__ __align__(16) unsigned short As[128][64];
    __shared__ __align__(16) unsigned short Bs[128][64];
    __shared__ unsigned long long rowms[2][128];     // [wc][tile row]
    __shared__ unsigned long long colms[2][128];     // [wr][tile col]

    const int i0 = blockIdx.y * 128;
    const int j0 = blockIdx.x * 128;
    const int t = threadIdx.x;
    const int wave = t >> 6, lane = t & 63;
    const int wr = wave >> 1, wc = wave & 1;   // 2x2 wave grid, each wave 64x64
    const int q = lane >> 4, cl = lane & 15;   // quad, col-lane

    f32x4 acc[4][4];    // acc[mi][ni]: (I-rows) x (C-rows)
    f32x4 acc2[4][4];   // acc2[ni][mi]: transposed product, same fragments
    #pragma unroll
    for (int a = 0; a < 4; ++a)
        #pragma unroll
        for (int b = 0; b < 4; ++b) {
            acc[a][b] = (f32x4){0.f, 0.f, 0.f, 0.f};
            acc2[a][b] = (f32x4){0.f, 0.f, 0.f, 0.f};
        }

    // Staging: waves 0,1 -> As halves; waves 2,3 -> Bs halves.
    // XOR swizzle: physical chunk p of LDS row r holds logical chunk p^(r&7);
    // this lane fetches logical chunk (lane&7)^(lane>>3).
    const int half = wave & 1;
    const unsigned short* sbase = (wave < 2)
        ? (Ib + (size_t)(i0 + half * 64) * DD)
        : (Cb + (size_t)(j0 + half * 64) * DD);
    const int srow = lane >> 3;                 // row within each 8-row issue
    const int schunk = (lane & 7) ^ srow;       // logical chunk index (0..7)

    for (int kk = 0; kk < DD; kk += 64) {
        #pragma unroll
        for (int it = 0; it < 8; ++it) {
            const unsigned short* g =
                sbase + (size_t)(it * 8 + srow) * DD + kk + schunk * 8;
            unsigned short* ldsbase = (wave < 2) ? &As[half * 64 + it * 8][0]
                                                 : &Bs[half * 64 + it * 8][0];
            __builtin_amdgcn_global_load_lds(
                (const __attribute__((address_space(1))) void*)g,
                (__attribute__((address_space(3))) void*)ldsbase,
                16, 0, 0);
        }
        __syncthreads();
        #pragma unroll
        for (int ks = 0; ks < 2; ++ks) {
            short8 af[4], bfr[4];
            const int pa = ((ks * 4 + q) ^ (cl & 7)) * 8;  // un-swizzled offset
            #pragma unroll
            for (int mi = 0; mi < 4; ++mi)
                af[mi] = *(const short8*)&As[wr * 64 + mi * 16 + cl][pa];
            #pragma unroll
            for (int ni = 0; ni < 4; ++ni)
                bfr[ni] = *(const short8*)&Bs[wc * 64 + ni * 16 + cl][pa];
            #pragma unroll
            for (int mi = 0; mi < 4; ++mi)
                #pragma unroll
                for (int ni = 0; ni < 4; ++ni) {
                    acc[mi][ni] = __builtin_amdgcn_mfma_f32_16x16x32_bf16(
                        af[mi], bfr[ni], acc[mi][ni], 0, 0, 0);
                    acc2[ni][mi] = __builtin_amdgcn_mfma_f32_16x16x32_bf16(
                        bfr[ni], af[mi], acc2[ni][mi], 0, 0, 0);
                }
        }
        __syncthreads();
    }

    // ---- col stats from acc: per lane, 16 in-reg elements (mi,r) share
    // column ni*16+cl; quads hold disjoint row subsets -> xor16/xor32 merge.
    #pragma unroll
    for (int ni = 0; ni < 4; ++ni) {
        float m = -INFINITY;
        #pragma unroll
        for (int mi = 0; mi < 4; ++mi)
            #pragma unroll
            for (int r = 0; r < 4; ++r)
                m = fmaxf(m, acc[mi][ni][r]);
        m = fmaxf(m, __shfl_xor(m, 16));
        m = fmaxf(m, __shfl_xor(m, 32));
        float s = 0.f;
        #pragma unroll
        for (int mi = 0; mi < 4; ++mi)
            #pragma unroll
            for (int r = 0; r < 4; ++r)
                s += __expf(acc[mi][ni][r] - m);
        s += __shfl_xor(s, 16);
        s += __shfl_xor(s, 32);
        if (q == 0) colms[wr][wc * 64 + ni * 16 + cl] = pack_ms(m, s);
    }

    // ---- row stats from acc2: per lane, 16 in-reg elements (ni,r) share
    // I-row mi*16+cl (summing over the wave's 64 C-rows).
    #pragma unroll
    for (int mi = 0; mi < 4; ++mi) {
        float m = -INFINITY;
        #pragma unroll
        for (int ni = 0; ni < 4; ++ni)
            #pragma unroll
            for (int r = 0; r < 4; ++r)
                m = fmaxf(m, acc2[ni][mi][r]);
        m = fmaxf(m, __shfl_xor(m, 16));
        m = fmaxf(m, __shfl_xor(m, 32));
        float s = 0.f;
        #pragma unroll
        for (int ni = 0; ni < 4; ++ni)
            #pragma unroll
            for (int r = 0; r < 4; ++r)
                s += __expf(acc2[ni][mi][r] - m);
        s += __shfl_xor(s, 16);
        s += __shfl_xor(s, 32);
        if (q == 0) rowms[wc][wr * 64 + mi * 16 + cl] = pack_ms(m, s);
    }

    __syncthreads();

    // ---- merge the two half-contributions, one store per row/col ----------
    if (t < 128) {
        row_part[(size_t)blockIdx.x * NN + i0 + t] =
            merge_ms(rowms[0][t], rowms[1][t]);
    } else {
        int c = t - 128;
        col_part[(size_t)blockIdx.y * NN + j0 + c] =
            merge_ms(colms[0][c], colms[1][c]);
    }
}

// Merge 64 partials per row and per col, combine with diag, reduce to loss.
__global__ __launch_bounds__(256) void reduce_kernel(
        const unsigned long long* __restrict__ row_part,
        const unsigned long long* __restrict__ col_part,
        const float* __restrict__ diag, float* out) {
    int idx = blockIdx.x * 256 + threadIdx.x;      // 0 .. 2*NN-1
    int r = (idx >= NN) ? idx - NN : idx;
    const unsigned long long* part = (idx >= NN) ? col_part : row_part;
    float m = -INFINITY, s = 0.f;
    #pragma unroll 4
    for (int p = 0; p < 64; ++p) {
        unsigned long long v = part[(size_t)p * NN + r];
        float pm = __uint_as_float((unsigned)(v & 0xffffffffull));
        float ps = __uint_as_float((unsigned)(v >> 32));
        float nm = fmaxf(m, pm);
        s = s * __expf(m - nm) + ps * __expf(pm - nm);
        m = nm;
    }
    float v = (m + logf(s) - diag[r]) * (0.5f / (float)NN);
    #pragma unroll
    for (int off = 32; off >= 1; off >>= 1) v += __shfl_xor(v, off);
    __shared__ float red[4];
    int wv = threadIdx.x >> 6, lane = threadIdx.x & 63;
    if (lane == 0) red[wv] = v;
    __syncthreads();
    if (threadIdx.x == 0) atomicAdd(out, red[0] + red[1] + red[2] + red[3]);
}

// ---- launch --------------------------------------------------------------

extern "C" void kernel_launch(void* const* d_in, const int* in_sizes, int n_in,
                              void* d_out, int out_size, void* d_ws, size_t ws_size,
                              hipStream_t stream) {
    const float* I = (const float*)d_in[0];
    const float* C = (const float*)d_in[1];
    float* out = (float*)d_out;
    char* ws = (char*)d_ws;

    // workspace layout (~16.1 MB)
    unsigned short* Ib = (unsigned short*)ws;                              // 4 MB
    unsigned short* Cb = (unsigned short*)(ws + (size_t)4 * 1024 * 1024);  // 4 MB
    unsigned long long* row_part =
        (unsigned long long*)(ws + (size_t)8 * 1024 * 1024);               // 4 MB
    unsigned long long* col_part =
        (unsigned long long*)(ws + (size_t)12 * 1024 * 1024);              // 4 MB
    float* diag = (float*)(ws + (size_t)16 * 1024 * 1024);                 // 32 KB

    convert_diag_kernel<<<2048, 256, 0, stream>>>(I, C, Ib, Cb, diag, out);
    dim3 grid(64, 64);
    gemm_lse_kernel<<<grid, 256, 0, stream>>>(Ib, Cb, row_part, col_part);
    reduce_kernel<<<64, 256, 0, stream>>>(row_part, col_part, diag, out);
}

// Round 6
// 123.445 us; speedup vs baseline: 5.5222x; 1.1562x over previous
//
#include <hip/hip_runtime.h>

#define NN 8192
#define DD 256
#define SCALE (1.0f / 0.07f)
// sqrt(1/0.07 * log2(e)): folded into both bf16 operands so MFMA output is
// logits in LOG2 domain (LSE_natural = ln2 * (m + log2(s))).
#define SQRT_SCALE_L2 4.539815983f
#define LN2F 0.6931471805599453f

typedef __attribute__((ext_vector_type(8))) short short8;
typedef __attribute__((ext_vector_type(4))) float f32x4;

// ---- helpers -------------------------------------------------------------

__device__ inline unsigned short f2bf(float x) {
    unsigned u = __float_as_uint(x);
    u += 0x7fffu + ((u >> 16) & 1u);   // round-to-nearest-even
    return (unsigned short)(u >> 16);
}

__device__ inline unsigned long long pack_ms(float m, float s) {
    return ((unsigned long long)__float_as_uint(s) << 32) |
           (unsigned long long)__float_as_uint(m);
}

// log2-domain (m, s) merge: state represents 2^m * s
__device__ inline void merge_ms(float& m, float& s, float pm, float ps) {
    float nm = fmaxf(m, pm);
    s = s * __builtin_amdgcn_exp2f(m - nm) + ps * __builtin_amdgcn_exp2f(pm - nm);
    m = nm;
}

// ---- kernels -------------------------------------------------------------

// Fused: bf16 convert (sqrt(SCALE*log2e) pre-scaling) + exact fp32 diagonal
// (natural units) + out zeroing. One wave = one 256-elem row.
__global__ __launch_bounds__(256) void convert_diag_kernel(
        const float* __restrict__ I, const float* __restrict__ C,
        unsigned short* __restrict__ Ib, unsigned short* __restrict__ Cb,
        float* __restrict__ diag, float* out) {
    if (blockIdx.x == 0 && threadIdx.x == 0) out[0] = 0.0f;
    int i = blockIdx.x * 256 + threadIdx.x;     // float4 chunk id
    float4 a = ((const float4*)I)[i];
    float4 b = ((const float4*)C)[i];
    ushort4 oa = make_ushort4(f2bf(a.x * SQRT_SCALE_L2), f2bf(a.y * SQRT_SCALE_L2),
                              f2bf(a.z * SQRT_SCALE_L2), f2bf(a.w * SQRT_SCALE_L2));
    ushort4 ob = make_ushort4(f2bf(b.x * SQRT_SCALE_L2), f2bf(b.y * SQRT_SCALE_L2),
                              f2bf(b.z * SQRT_SCALE_L2), f2bf(b.w * SQRT_SCALE_L2));
    ((ushort4*)Ib)[i] = oa;
    ((ushort4*)Cb)[i] = ob;
    float s = a.x * b.x + a.y * b.y + a.z * b.z + a.w * b.w;
    #pragma unroll
    for (int off = 32; off >= 1; off >>= 1) s += __shfl_xor(s, off);
    if ((threadIdx.x & 63) == 0) diag[i >> 6] = s * SCALE;
}

// 128x128 logits tile per block. Single MFMA product; EXACT per-col refs
// (in-register) and EXACT per-row refs (max-butterfly + LDS broadcast).
__global__ __launch_bounds__(256, 4) void gemm_lse_kernel(
        const unsigned short* __restrict__ Ib,
        const unsigned short* __restrict__ Cb,
        unsigned long long* __restrict__ row_part,   // [64 (bx)][NN]
        unsigned long long* __restrict__ col_part) { // [64 (by)][NN]
    __shared__ __align__(16) unsigned short As[128][64];
    __shared__ __align__(16) unsigned short Bs[128][64];
    __shared__ unsigned long long rowms[2][128];     // [wc][tile row]
    __shared__ unsigned long long colms[2][128];     // [wr][tile col]
    __shared__ __align__(16) float rmx[4][64];       // [wave][q*16 + j] row maxes

    const int i0 = blockIdx.y * 128;
    const int j0 = blockIdx.x * 128;
    const int t = threadIdx.x;
    const int wave = t >> 6, lane = t & 63;
    const int wr = wave >> 1, wc = wave & 1;   // 2x2 wave grid, each wave 64x64
    const int q = lane >> 4, cl = lane & 15;   // quad, col-lane

    f32x4 acc[4][4];    // acc[mi][ni]: row wr*64+mi*16+q*4+r, col wc*64+ni*16+cl
    #pragma unroll
    for (int mi = 0; mi < 4; ++mi)
        #pragma unroll
        for (int ni = 0; ni < 4; ++ni)
            acc[mi][ni] = (f32x4){0.f, 0.f, 0.f, 0.f};

    // Staging: waves 0,1 -> As halves; waves 2,3 -> Bs halves.
    // XOR swizzle: physical chunk p of LDS row r holds logical chunk p^(r&7).
    const int half = wave & 1;
    const unsigned short* sbase = (wave < 2)
        ? (Ib + (size_t)(i0 + half * 64) * DD)
        : (Cb + (size_t)(j0 + half * 64) * DD);
    const int srow = lane >> 3;                 // row within each 8-row issue
    const int schunk = (lane & 7) ^ srow;       // logical chunk index (0..7)

    for (int kk = 0; kk < DD; kk += 64) {
        #pragma unroll
        for (int it = 0; it < 8; ++it) {
            const unsigned short* g =
                sbase + (size_t)(it * 8 + srow) * DD + kk + schunk * 8;
            unsigned short* ldsbase = (wave < 2) ? &As[half * 64 + it * 8][0]
                                                 : &Bs[half * 64 + it * 8][0];
            __builtin_amdgcn_global_load_lds(
                (const __attribute__((address_space(1))) void*)g,
                (__attribute__((address_space(3))) void*)ldsbase,
                16, 0, 0);
        }
        __syncthreads();
        #pragma unroll
        for (int ks = 0; ks < 2; ++ks) {
            short8 af[4], bfr[4];
            const int pa = ((ks * 4 + q) ^ (cl & 7)) * 8;  // un-swizzled offset
            #pragma unroll
            for (int mi = 0; mi < 4; ++mi)
                af[mi] = *(const short8*)&As[wr * 64 + mi * 16 + cl][pa];
            #pragma unroll
            for (int ni = 0; ni < 4; ++ni)
                bfr[ni] = *(const short8*)&Bs[wc * 64 + ni * 16 + cl][pa];
            #pragma unroll
            for (int mi = 0; mi < 4; ++mi)
                #pragma unroll
                for (int ni = 0; ni < 4; ++ni)
                    acc[mi][ni] = __builtin_amdgcn_mfma_f32_16x16x32_bf16(
                        af[mi], bfr[ni], acc[mi][ni], 0, 0, 0);
        }
        __syncthreads();
    }

    // ==== col stats: exact per-col max, all in-register + 2 shuffles =======
    #pragma unroll
    for (int ni = 0; ni < 4; ++ni) {
        float m = acc[0][ni][0];
        #pragma unroll
        for (int mi = 0; mi < 4; ++mi)
            #pragma unroll
            for (int r = 0; r < 4; ++r)
                m = fmaxf(m, acc[mi][ni][r]);
        m = fmaxf(m, __shfl_xor(m, 16));
        m = fmaxf(m, __shfl_xor(m, 32));
        float s = 0.f;
        #pragma unroll
        for (int mi = 0; mi < 4; ++mi)
            #pragma unroll
            for (int r = 0; r < 4; ++r)
                s += __builtin_amdgcn_exp2f(acc[mi][ni][r] - m);
        s += __shfl_xor(s, 16);
        s += __shfl_xor(s, 32);
        if (q == 0) colms[wr][wc * 64 + ni * 16 + cl] = pack_ms(m, s);
    }

    // ==== row stats: exact per-row max via butterfly + LDS broadcast =======
    // v[j], j = mi*4+r: partial row max over this lane's 4 cols (ni=0..3)
    float v[16];
    #pragma unroll
    for (int mi = 0; mi < 4; ++mi)
        #pragma unroll
        for (int r = 0; r < 4; ++r)
            v[mi * 4 + r] = fmaxf(fmaxf(acc[mi][0][r], acc[mi][1][r]),
                                  fmaxf(acc[mi][2][r], acc[mi][3][r]));
    // MAX butterfly across the 16-lane cl-group; lane cl ends owning the
    // full 64-col max of row index bitrev4(cl).
    #pragma unroll
    for (int d = 0, n = 8; d < 4; ++d, n >>= 1) {
        const bool upper = (cl >> d) & 1;
        #pragma unroll
        for (int j = 0; j < 8; ++j) {
            if (j >= n) break;
            float send = upper ? v[j] : v[j + n];
            float recv = __shfl_xor(send, 1 << d);
            v[j] = fmaxf(upper ? v[j + n] : v[j], recv);
        }
    }
    const int brcl = ((cl & 1) << 3) | ((cl & 2) << 1) |
                     ((cl >> 1) & 2) | ((cl >> 3) & 1);   // bitrev4(cl)
    const float rm_own = v[0];          // row max of row j=brcl (this q group)
    rmx[wave][q * 16 + brcl] = rm_own;
    __syncthreads();
    // broadcast back: rm[j] for all 16 rows of this (wave, q) group
    float4 rm4[4];
    #pragma unroll
    for (int mi = 0; mi < 4; ++mi)
        rm4[mi] = *(const float4*)&rmx[wave][q * 16 + mi * 4];

    // row-referenced exps, partial sums over this lane's 4 cols
    #pragma unroll
    for (int mi = 0; mi < 4; ++mi)
        #pragma unroll
        for (int r = 0; r < 4; ++r) {
            float ref = ((const float*)&rm4[mi])[r];
            v[mi * 4 + r] =
                __builtin_amdgcn_exp2f(acc[mi][0][r] - ref) +
                __builtin_amdgcn_exp2f(acc[mi][1][r] - ref) +
                __builtin_amdgcn_exp2f(acc[mi][2][r] - ref) +
                __builtin_amdgcn_exp2f(acc[mi][3][r] - ref);
        }
    // ADD butterfly: lane cl ends owning the full row sum of row bitrev4(cl)
    #pragma unroll
    for (int d = 0, n = 8; d < 4; ++d, n >>= 1) {
        const bool upper = (cl >> d) & 1;
        #pragma unroll
        for (int j = 0; j < 8; ++j) {
            if (j >= n) break;
            float send = upper ? v[j] : v[j + n];
            float recv = __shfl_xor(send, 1 << d);
            v[j] = (upper ? v[j + n] : v[j]) + recv;
        }
    }
    const int rmi = brcl >> 2, rr = brcl & 3;
    rowms[wc][wr * 64 + rmi * 16 + q * 4 + rr] = pack_ms(rm_own, v[0]);

    __syncthreads();

    // ---- merge the two half-contributions, one store per row/col ----------
    if (t < 128) {
        unsigned long long a = rowms[0][t], b = rowms[1][t];
        float m = __uint_as_float((unsigned)(a & 0xffffffffull));
        float s = __uint_as_float((unsigned)(a >> 32));
        merge_ms(m, s, __uint_as_float((unsigned)(b & 0xffffffffull)),
                 __uint_as_float((unsigned)(b >> 32)));
        row_part[(size_t)blockIdx.x * NN + i0 + t] = pack_ms(m, s);
    } else {
        int c = t - 128;
        unsigned long long a = colms[0][c], b = colms[1][c];
        float m = __uint_as_float((unsigned)(a & 0xffffffffull));
        float s = __uint_as_float((unsigned)(a >> 32));
        merge_ms(m, s, __uint_as_float((unsigned)(b & 0xffffffffull)),
                 __uint_as_float((unsigned)(b >> 32)));
        col_part[(size_t)blockIdx.y * NN + j0 + c] = pack_ms(m, s);
    }
}

// Merge 64 partials per row/col: 8 threads per row, 8 partials each,
// 3-level shuffle merge, then combine with diag and reduce to the loss.
__global__ __launch_bounds__(256) void reduce_kernel(
        const unsigned long long* __restrict__ row_part,
        const unsigned long long* __restrict__ col_part,
        const float* __restrict__ diag, float* out) {
    int gid = blockIdx.x * 256 + threadIdx.x;      // 0 .. 2*NN*8-1
    int row = gid >> 3;                            // 0 .. 2*NN-1
    int sub = gid & 7;
    int r = (row >= NN) ? row - NN : row;
    const unsigned long long* part = (row >= NN) ? col_part : row_part;

    float m = -INFINITY, s = 0.f;
    #pragma unroll
    for (int i = 0; i < 8; ++i) {
        unsigned long long vp = part[(size_t)(sub * 8 + i) * NN + r];
        float pm = __uint_as_float((unsigned)(vp & 0xffffffffull));
        float ps = __uint_as_float((unsigned)(vp >> 32));
        merge_ms(m, s, pm, ps);
    }
    #pragma unroll
    for (int off = 1; off < 8; off <<= 1) {
        float pm = __shfl_xor(m, off);
        float ps = __shfl_xor(s, off);
        merge_ms(m, s, pm, ps);
    }
    float v = 0.f;
    if (sub == 0)
        v = (LN2F * (m + __builtin_amdgcn_logf(s)) - diag[r]) * (0.5f / (float)NN);
    #pragma unroll
    for (int off = 1; off < 64; off <<= 1) v += __shfl_xor(v, off);
    __shared__ float red[4];
    int wv = threadIdx.x >> 6, lane = threadIdx.x & 63;
    if (lane == 0) red[wv] = v;
    __syncthreads();
    if (threadIdx.x == 0) atomicAdd(out, red[0] + red[1] + red[2] + red[3]);
}

// ---- launch --------------------------------------------------------------

extern "C" void kernel_launch(void* const* d_in, const int* in_sizes, int n_in,
                              void* d_out, int out_size, void* d_ws, size_t ws_size,
                              hipStream_t stream) {
    const float* I = (const float*)d_in[0];
    const float* C = (const float*)d_in[1];
    float* out = (float*)d_out;
    char* ws = (char*)d_ws;

    // workspace layout (~16.1 MB)
    unsigned short* Ib = (unsigned short*)ws;                              // 4 MB
    unsigned short* Cb = (unsigned short*)(ws + (size_t)4 * 1024 * 1024);  // 4 MB
    unsigned long long* row_part =
        (unsigned long long*)(ws + (size_t)8 * 1024 * 1024);               // 4 MB
    unsigned long long* col_part =
        (unsigned long long*)(ws + (size_t)12 * 1024 * 1024);              // 4 MB
    float* diag = (float*)(ws + (size_t)16 * 1024 * 1024);                 // 32 KB

    convert_diag_kernel<<<2048, 256, 0, stream>>>(I, C, Ib, Cb, diag, out);
    dim3 grid(64, 64);
    gemm_lse_kernel<<<grid, 256, 0, stream>>>(Ib, Cb, row_part, col_part);
    reduce_kernel<<<512, 256, 0, stream>>>(row_part, col_part, diag, out);
}